// Round 14
// baseline (30.069 us; speedup 1.0000x reference)
//
#include <hip/hip_runtime.h>
#include <stdint.h>

#define BB 512
#define TT 500
#define KK 64
#define DD 64

typedef unsigned long long ull;

// WS: tbm[512][8][64] u64 (2 MiB) | ybm same | params4[64] | p1i[64].
// Every (b,w,k) word is owned by exactly one block of kernel A and written
// unconditionally -> no zeroing pass needed.

// ---------------- kernel A: block = (b, window-pair p) ----------------
// 256 threads: thread i -> row 128p + (i>>1), half h = i&1 (64 B of the row).
// 4 (bf16) / 8 (f32) independent uint4 loads, burst-issued; LDS bitmap build;
// coalesced unconditional store of 2 windows x 64 k words per plane.
__launch_bounds__(256, 8)
__global__ void ev_quad(const uint32_t* __restrict__ chainw,
                        const int* __restrict__ corr,
                        const float* __restrict__ embd,
                        const float* __restrict__ Wf,
                        const float* __restrict__ bias,
                        ull* __restrict__ tbm,
                        ull* __restrict__ ybm,
                        float4* __restrict__ params4,
                        float* __restrict__ p1i) {
    __shared__ ull tmask[2 * KK];
    __shared__ ull ymask[2 * KK];

    const int tid = threadIdx.x;
    const int lane = tid & 63;
    const int bp = blockIdx.x;
    const int b = bp >> 2, p = bp & 3;
    const int row = p * 128 + (tid >> 1);        // row within b
    const int h = tid & 1;
    const bool live = (row < TT);

    // ---- dtype sniff: f32 one-hot row 0 -> 1 nonzero word in first 64; bf16 -> 2 ----
    uint32_t sv = chainw[lane];
    ull sm = __ballot(sv != 0u);
    const bool isb = (__popcll(sm) >= 2);

    // ---- burst loads (issued before LDS zero / barrier) ----
    uint4 r[8];
    int nq;
    if (isb) {                                   // bf16: half-row = 64 B = 4 uint4
        nq = 4;
        const uint4* rp = (const uint4*)chainw + (((size_t)b * TT + row) << 3) + h * 4;
        if (live) {
#pragma unroll
            for (int q = 0; q < 4; ++q) r[q] = rp[q];
        }
    } else {                                     // f32: half-row = 128 B = 8 uint4
        nq = 8;
        const uint4* rp = (const uint4*)chainw + (((size_t)b * TT + row) << 4) + h * 8;
        if (live) {
#pragma unroll
            for (int q = 0; q < 8; ++q) r[q] = rp[q];
        }
    }
    int y = 0;
    if (live) y = corr[b * TT + row] & 1;

    // ---- zero LDS (128 words/plane) ----
    if (tid < 128) { tmask[tid] = 0; ymask[tid] = 0; }

    // ---- params: block 0, lanes 0..63 (one-time; overlaps loads elsewhere) ----
    if (bp == 0 && tid < KK) {
        float l0 = bias[0], l1 = bias[1], l2 = bias[2], l3 = bias[3], l4 = bias[4];
        const float4* er = (const float4*)(embd + tid * DD);
#pragma unroll 4
        for (int d4 = 0; d4 < DD / 4; ++d4) {
            float4 e = er[d4];
            float4 a;
            a = ((const float4*)(Wf + 0 * DD))[d4]; l0 = fmaf(e.x,a.x,fmaf(e.y,a.y,fmaf(e.z,a.z,fmaf(e.w,a.w,l0))));
            a = ((const float4*)(Wf + 1 * DD))[d4]; l1 = fmaf(e.x,a.x,fmaf(e.y,a.y,fmaf(e.z,a.z,fmaf(e.w,a.w,l1))));
            a = ((const float4*)(Wf + 2 * DD))[d4]; l2 = fmaf(e.x,a.x,fmaf(e.y,a.y,fmaf(e.z,a.z,fmaf(e.w,a.w,l2))));
            a = ((const float4*)(Wf + 3 * DD))[d4]; l3 = fmaf(e.x,a.x,fmaf(e.y,a.y,fmaf(e.z,a.z,fmaf(e.w,a.w,l3))));
            a = ((const float4*)(Wf + 4 * DD))[d4]; l4 = fmaf(e.x,a.x,fmaf(e.y,a.y,fmaf(e.z,a.z,fmaf(e.w,a.w,l4))));
        }
        auto sig = [](float x) { return 1.0f / (1.0f + __expf(-x)); };
        params4[tid] = make_float4(sig(2.f*l2),    // g0 = p(y=1|s=0)
                                   sig(-2.f*l3),   // g1 = p(y=1|s=1)
                                   sig(2.f*l0),    // t10 = p(s'=1|s=0)
                                   sig(-2.f*l1));  // t11 = p(s'=1|s=1)
        p1i[tid] = sig(2.f*l4);
    }
    __syncthreads();

    // ---- find k in this half-row ----
    int k = -1;
    if (live) {
        if (isb) {
#pragma unroll
            for (int q = 0; q < 4; ++q) {
                uint4 v = r[q];
                if ((v.x | v.y | v.z | v.w) != 0u) {
                    int widx; uint32_t nw;
                    if (v.x)      { widx = 0; nw = v.x; }
                    else if (v.y) { widx = 1; nw = v.y; }
                    else if (v.z) { widx = 2; nw = v.z; }
                    else          { widx = 3; nw = v.w; }
                    k = h * 32 + q * 8 + widx * 2 + ((nw >> 16) ? 1 : 0);
                }
            }
        } else {
#pragma unroll
            for (int q = 0; q < 8; ++q) {
                uint4 v = r[q];
                if ((v.x | v.y | v.z | v.w) != 0u) {
                    int widx;
                    if (v.x)      widx = 0;
                    else if (v.y) widx = 1;
                    else if (v.z) widx = 2;
                    else          widx = 3;
                    k = h * 32 + q * 4 + widx;
                }
            }
        }
    }

    // ---- deposit bits: window index within pair = (row>>6)&1, bit = row&63 ----
    if (k >= 0) {
        const int wl = (row >> 6) & 1;
        const ull bit = 1ull << (row & 63);
        atomicOr(&tmask[wl * KK + k], bit);
        if (y) atomicOr(&ymask[wl * KK + k], bit);
    }
    __syncthreads();

    // ---- unconditional coalesced store: 2 windows x 64 words per plane ----
    if (tid < 128) {
        const int w = p * 2 + (tid >> 6);         // global window 0..7
        const size_t o = (((size_t)b * 8 + w) << 6) + (tid & 63);
        tbm[o] = tmask[tid];
        ybm[o] = ymask[tid];
    }
}

// ---------------- kernel B: thread = (b,k); ctz-walk bitmap, scalar filter ----------------
__launch_bounds__(256, 8)
__global__ void bkt_bits(const ull* __restrict__ tbm,
                         const ull* __restrict__ ybm,
                         const float4* __restrict__ params4,
                         const float* __restrict__ p1i,
                         float2* __restrict__ out) {
    const int lane = threadIdx.x & 63;           // = k
    const int b = blockIdx.x * 4 + (threadIdx.x >> 6);

    const ull* tp = tbm + ((size_t)b << 9) + lane;   // [b][w][k]
    const ull* yp = ybm + ((size_t)b << 9) + lane;
    ull tm[8], ym[8];
#pragma unroll
    for (int w = 0; w < 8; ++w) tm[w] = tp[(size_t)w << 6];
#pragma unroll
    for (int w = 0; w < 8; ++w) ym[w] = yp[(size_t)w << 6];

    const float4 P = params4[lane];
    const float g0 = P.x, g1 = P.y, t10 = P.z, t11 = P.w;
    const float dg = g1 - g0, dt = t11 - t10, g1c = 1.f - g1;
    float p1 = p1i[lane];

    float2* ob = out + (size_t)b * TT;
#pragma unroll
    for (int w = 0; w < 8; ++w) {
        ull tb = tm[w];
        const ull yb = ym[w];
        while (tb) {
            int j = __builtin_ctzll(tb);
            tb &= tb - 1;
            int t = w * 64 + j;
            int yy = (int)((yb >> j) & 1ull);
            float pe1 = fmaf(p1, dg, g0);
            float pe0 = 1.f - pe1;
            ob[t] = make_float2(__logf(pe0), __logf(pe1));
            float gy  = yy ? g1  : g1c;
            float pyy = yy ? pe1 : pe0;
            p1 = fmaf(p1 * __fdividef(gy, pyy), dt, t10);
        }
    }
}

extern "C" void kernel_launch(void* const* d_in, const int* in_sizes, int n_in,
                              void* d_out, int out_size, void* d_ws, size_t ws_size,
                              hipStream_t stream) {
    // Identify inputs by flat element count (robust to ordering).
    const void* p_corr = nullptr, *p_chain = nullptr, *p_embd = nullptr,
              * p_Wf = nullptr, *p_bias = nullptr;
    for (int i = 0; i < n_in; ++i) {
        switch (in_sizes[i]) {
            case BB * TT:        p_corr  = d_in[i]; break;   // 256000
            case BB * TT * KK:   p_chain = d_in[i]; break;   // 16384000
            case KK * DD:        p_embd  = d_in[i]; break;   // 4096
            case 5 * DD:         p_Wf    = d_in[i]; break;   // 320
            case 5:              p_bias  = d_in[i]; break;
            default: break;
        }
    }
    if (!p_corr)  p_corr  = d_in[0];
    if (!p_chain) p_chain = d_in[1];
    if (!p_embd)  p_embd  = d_in[2];
    if (!p_Wf)    p_Wf    = d_in[3];
    if (!p_bias)  p_bias  = d_in[4];
    (void)out_size;

    const size_t PLANE = (size_t)BB * 8 * KK * 8;            // 2 MiB
    ull*    tbm     = (ull*)d_ws;
    ull*    ybm     = (ull*)((char*)d_ws + PLANE);
    float4* params4 = (float4*)((char*)d_ws + 2 * PLANE);
    float*  p1i     = (float*)((char*)d_ws + 2 * PLANE + KK * 16);

    ev_quad<<<BB * 4, 256, 0, stream>>>((const uint32_t*)p_chain,
                                        (const int*)p_corr,
                                        (const float*)p_embd,
                                        (const float*)p_Wf,
                                        (const float*)p_bias,
                                        tbm, ybm, params4, p1i);
    bkt_bits<<<BB / 4, 256, 0, stream>>>(tbm, ybm, params4, p1i, (float2*)d_out);
}

// Round 15
// 24.584 us; speedup vs baseline: 1.2231x; 1.2231x over previous
//
#include <hip/hip_runtime.h>
#include <stdint.h>

#define BB 512
#define TT 500
#define KK 64
#define DD 64

typedef unsigned long long ull;

// One 1024-thread block per b (2 blocks/CU = 32 waves/CU). Zero global scratch.
// Waves 1..15 stream chain as uint2 chunks (512 B coalesced per instr):
//   bf16 chunk = 4 rows, f32 chunk = 2 rows; the owner lane of each row's
//   unique nonzero word computes k locally and LDS-atomicOr's bit (row&63)
//   into tmask[row>>6][k]. Wave 0 meanwhile computes per-k params (regs) and
//   stages corr into LDS. One barrier, then wave 0 (lane=k) ctz-walks its
//   ~8 events and writes float2 log-probs.
__launch_bounds__(1024, 8)
__global__ void bkt_fused(const uint32_t* __restrict__ chainw,
                          const int* __restrict__ corr,
                          const float* __restrict__ embd,
                          const float* __restrict__ Wf,
                          const float* __restrict__ bias,
                          float2* __restrict__ out) {
    __shared__ ull tmask[8][KK];                 // 4 KB
    __shared__ uint32_t corr_s[TT];              // 2 KB

    const int b = blockIdx.x;
    const int tid = threadIdx.x;
    const int wv = tid >> 6, lane = tid & 63;

    // ---- dtype sniff: f32 one-hot row 0 -> 1 nonzero word in first 64; bf16 -> 2 ----
    uint32_t sv = chainw[lane];
    ull sm = __ballot(sv != 0u);
    const bool isb = (__popcll(sm) >= 2);

    // ---- zero bitmap (512 words), visible to all depositor waves ----
    if (tid < 512) ((ull*)tmask)[tid] = 0;
    __syncthreads();

    float g0 = 0.f, g1 = 0.f, t10 = 0.f, t11 = 0.f, p1 = 0.f;

    if (wv == 0) {
        // ---- per-k params in registers (lane = k); L2-hot weights ----
        float l0 = bias[0], l1 = bias[1], l2 = bias[2], l3 = bias[3], l4 = bias[4];
        const float4* er = (const float4*)(embd + lane * DD);
#pragma unroll 4
        for (int d4 = 0; d4 < DD / 4; ++d4) {
            float4 e = er[d4];
            float4 a;
            a = ((const float4*)(Wf + 0 * DD))[d4]; l0 = fmaf(e.x,a.x,fmaf(e.y,a.y,fmaf(e.z,a.z,fmaf(e.w,a.w,l0))));
            a = ((const float4*)(Wf + 1 * DD))[d4]; l1 = fmaf(e.x,a.x,fmaf(e.y,a.y,fmaf(e.z,a.z,fmaf(e.w,a.w,l1))));
            a = ((const float4*)(Wf + 2 * DD))[d4]; l2 = fmaf(e.x,a.x,fmaf(e.y,a.y,fmaf(e.z,a.z,fmaf(e.w,a.w,l2))));
            a = ((const float4*)(Wf + 3 * DD))[d4]; l3 = fmaf(e.x,a.x,fmaf(e.y,a.y,fmaf(e.z,a.z,fmaf(e.w,a.w,l3))));
            a = ((const float4*)(Wf + 4 * DD))[d4]; l4 = fmaf(e.x,a.x,fmaf(e.y,a.y,fmaf(e.z,a.z,fmaf(e.w,a.w,l4))));
        }
        auto sig = [](float x) { return 1.0f / (1.0f + __expf(-x)); };
        t10 = sig( 2.f * l0);    // p(s'=1 | s=0)
        t11 = sig(-2.f * l1);    // p(s'=1 | s=1)
        g0  = sig( 2.f * l2);    // p(y=1 | s=0)
        g1  = sig(-2.f * l3);    // p(y=1 | s=1)
        p1  = sig( 2.f * l4);    // initial p(s=1)

        // ---- corr -> LDS (wave-local; barrier below orders vs walk) ----
        const uint32_t* cp = (const uint32_t*)corr + (size_t)b * TT;
#pragma unroll
        for (int i = 0; i < 8; ++i) {
            int idx = i * 64 + lane;
            if (idx < TT) corr_s[idx] = cp[idx];
        }
    } else {
        const int sw = wv - 1;                   // streaming wave id 0..14
        if (isb) {
            // bf16: chunk = 512 B = 4 rows; 125 chunks. lane j=lane&15 holds
            // halfwords 4j..4j+3 of row 4m + (lane>>4).
            const uint32_t* base = chainw + (size_t)b * (TT * 32);
            uint2 rv[9];
#pragma unroll
            for (int i = 0; i < 9; ++i) {
                int m = sw + 15 * i;
                if (m < 125) rv[i] = *(const uint2*)(base + m * 128 + 2 * lane);
            }
#pragma unroll
            for (int i = 0; i < 9; ++i) {
                int m = sw + 15 * i;
                if (m < 125) {
                    uint2 v = rv[i];
                    if ((v.x | v.y) != 0u) {
                        int j = lane & 15;
                        int k = 4 * j + ((v.x & 0xFFFFu) ? 0 : (v.x >> 16) ? 1
                                       : (v.y & 0xFFFFu) ? 2 : 3);
                        int r = 4 * m + (lane >> 4);
                        atomicOr(&tmask[r >> 6][k], 1ull << (r & 63));
                    }
                }
            }
        } else {
            // f32: chunk = 512 B = 2 rows; 250 chunks. lane j=lane&31 holds
            // elements 2j,2j+1 of row 2m + (lane>>5).
            const uint32_t* base = chainw + (size_t)b * (TT * 64);
            uint2 rv[17];
#pragma unroll
            for (int i = 0; i < 17; ++i) {
                int m = sw + 15 * i;
                if (m < 250) rv[i] = *(const uint2*)(base + m * 128 + 2 * lane);
            }
#pragma unroll
            for (int i = 0; i < 17; ++i) {
                int m = sw + 15 * i;
                if (m < 250) {
                    uint2 v = rv[i];
                    if ((v.x | v.y) != 0u) {
                        int k = 2 * (lane & 31) + (v.x ? 0 : 1);
                        int r = 2 * m + (lane >> 5);
                        atomicOr(&tmask[r >> 6][k], 1ull << (r & 63));
                    }
                }
            }
        }
    }
    __syncthreads();

    // ---- phase 2: wave 0, lane = k: ctz-walk + scalar filter ----
    if (wv == 0) {
        const float dg = g1 - g0, dt = t11 - t10, g1c = 1.f - g1;
        float2* ob = out + (size_t)b * TT;
#pragma unroll
        for (int w = 0; w < 8; ++w) {
            ull tb = tmask[w][lane];
            while (tb) {
                int j = __builtin_ctzll(tb);
                tb &= tb - 1;
                int t = w * 64 + j;
                int yy = (int)(corr_s[t] & 1u);
                float pe1 = fmaf(p1, dg, g0);
                float pe0 = 1.f - pe1;
                ob[t] = make_float2(__logf(pe0), __logf(pe1));
                float gy  = yy ? g1  : g1c;
                float pyy = yy ? pe1 : pe0;
                p1 = fmaf(p1 * __fdividef(gy, pyy), dt, t10);
            }
        }
    }
}

extern "C" void kernel_launch(void* const* d_in, const int* in_sizes, int n_in,
                              void* d_out, int out_size, void* d_ws, size_t ws_size,
                              hipStream_t stream) {
    // Identify inputs by flat element count (robust to ordering).
    const void* p_corr = nullptr, *p_chain = nullptr, *p_embd = nullptr,
              * p_Wf = nullptr, *p_bias = nullptr;
    for (int i = 0; i < n_in; ++i) {
        switch (in_sizes[i]) {
            case BB * TT:        p_corr  = d_in[i]; break;   // 256000
            case BB * TT * KK:   p_chain = d_in[i]; break;   // 16384000
            case KK * DD:        p_embd  = d_in[i]; break;   // 4096
            case 5 * DD:         p_Wf    = d_in[i]; break;   // 320
            case 5:              p_bias  = d_in[i]; break;
            default: break;
        }
    }
    if (!p_corr)  p_corr  = d_in[0];
    if (!p_chain) p_chain = d_in[1];
    if (!p_embd)  p_embd  = d_in[2];
    if (!p_Wf)    p_Wf    = d_in[3];
    if (!p_bias)  p_bias  = d_in[4];
    (void)d_ws; (void)ws_size; (void)out_size;

    bkt_fused<<<BB, 1024, 0, stream>>>((const uint32_t*)p_chain,
                                       (const int*)p_corr,
                                       (const float*)p_embd,
                                       (const float*)p_Wf,
                                       (const float*)p_bias,
                                       (float2*)d_out);
}